// Round 6
// baseline (127.176 us; speedup 1.0000x reference)
//
#include <hip/hip_runtime.h>
#include <stdint.h>

// YOLO-style loss, faithful to the (buggy) reference _xyxy: center = w/S for both x and y.
// loss = (5*(xy+wh) + obj + 0.5*noobj) / 1024, summed over 1024*80*80 cells.
//
// R5: global_load_lds 2-phase counted-vmcnt pipeline.
//  - R0/R1/R2 (3 structures) all ~56us at ~4.75 TB/s delivered -> per-CU L1 MSHR
//    concurrency cap with mixed L3/HBM latency, not bandwidth. Fill kernel does 7.2 TB/s.
//  - NT loads (R3/R4) regressed: 16B-granular NT = no L2 allocate = 4-5x fabric
//    transactions. Reverted.
//  - pred (80B/group stream) staged global->LDS async (bypasses L1, no VGPR round trip),
//    40KB of loads in flight per block; targ+mask pipelined into registers.
//  - s_waitcnt vmcnt(10) keeps next tile's 10 vmem ops in flight across the barrier.

#define S_INV (1.0f / 80.0f)

typedef float f4 __attribute__((ext_vector_type(4)));
typedef int   i4 __attribute__((ext_vector_type(4)));

#define TILE_GROUPS 256
#define PRED_TILE_B (TILE_GROUPS * 80)   // 20480 bytes per tile (5 f4 per group)

__global__ void zero_out_kernel(float* out) { out[0] = 0.0f; }

__device__ __forceinline__ void async16(const void* g, void* l) {
    __builtin_amdgcn_global_load_lds(
        (const __attribute__((address_space(1))) void*)g,
        (__attribute__((address_space(3))) void*)l, 16, 0, 0);
}

// pipeline sync: wait with N vmem still in flight, then block barrier.
#define PIPE_WAIT_BARRIER_10() do {                          \
    asm volatile("s_waitcnt vmcnt(10)" ::: "memory");        \
    __builtin_amdgcn_s_barrier();                            \
    asm volatile("" ::: "memory");                           \
} while (0)

#define PIPE_WAIT_BARRIER_0() do {                           \
    asm volatile("s_waitcnt vmcnt(0)" ::: "memory");         \
    __builtin_amdgcn_s_barrier();                            \
    asm volatile("" ::: "memory");                           \
} while (0)

#define PIPE_END_BARRIER() do {                              \
    asm volatile("s_waitcnt lgkmcnt(0)" ::: "memory");       \
    __builtin_amdgcn_s_barrier();                            \
    asm volatile("" ::: "memory");                           \
} while (0)

struct TM { f4 t0, t1, t2, t3; i4 m; };

__device__ __forceinline__ void load_tm(TM& tm, const f4* __restrict__ targ4,
                                        const i4* __restrict__ mask4, int gid) {
    tm.t0 = targ4[4 * gid + 0];
    tm.t1 = targ4[4 * gid + 1];
    tm.t2 = targ4[4 * gid + 2];
    tm.t3 = targ4[4 * gid + 3];
    tm.m  = mask4[gid];
}

// stage one tile's pred (20480 B) into LDS buffer: 20 chunks of 1KB, wave w does
// chunks {w, 4+w, 8+w, 12+w, 16+w}; lane l writes bytes [16l,16l+16) of its chunk.
__device__ __forceinline__ void stage_pred(const char* __restrict__ predB, char* buf,
                                           int tile, int wave, int lane) {
    const char* src = predB + (size_t)tile * PRED_TILE_B;
    #pragma unroll
    for (int i = 0; i < 5; ++i) {
        int off = (i * 4 + wave) * 1024;
        async16(src + off + lane * 16, buf + off);
    }
}

__device__ __forceinline__ float cell_loss(float px, float py, float pw, float ph, float pc,
                                           float tx, float ty, float tw, float th, int m)
{
    // _xyxy (faithful to reference bug: center is w/S for BOTH axes)
    float cp = pw * S_INV;
    float ct = tw * S_INV;
    float px1 = cp - 0.5f * pw, py1 = cp - 0.5f * ph;
    float px2 = cp + 0.5f * pw, py2 = cp + 0.5f * ph;
    float tx1 = ct - 0.5f * tw, ty1 = ct - 0.5f * th;
    float tx2 = ct + 0.5f * tw, ty2 = ct + 0.5f * th;

    float iw = fmaxf(fminf(px2, tx2) - fmaxf(px1, tx1), 0.0f);
    float ih = fmaxf(fminf(py2, ty2) - fmaxf(py1, ty1), 0.0f);
    float inter = iw * ih;
    float uni = pw * ph + tw * th - inter;
    float iou = inter / uni;

    float dx = px - tx, dy = py - ty;
    float sw = sqrtf(pw) - sqrtf(tw);
    float sh = sqrtf(ph) - sqrtf(th);
    float dobj = pc - iou;

    float obj_term = 5.0f * ((dx * dx + dy * dy) + (sw * sw + sh * sh)) + dobj * dobj;
    float noobj_term = 0.5f * pc * pc;
    return (m > 0) ? obj_term : noobj_term;
}

// compute thread t's 4 cells; pred from LDS (smem_base points at this tile's buffer)
__device__ __forceinline__ float compute_tile(const char* smem_base, const TM& tm, int t) {
    const f4* lp = (const f4*)(smem_base + t * 80);
    f4 p0 = lp[0], p1 = lp[1], p2 = lp[2], p3 = lp[3], p4 = lp[4];
    float s = 0.0f;
    s += cell_loss(p0.x, p0.y, p0.z, p0.w, p1.x,
                   tm.t0.x, tm.t0.y, tm.t0.z, tm.t0.w, tm.m.x);
    s += cell_loss(p1.y, p1.z, p1.w, p2.x, p2.y,
                   tm.t1.x, tm.t1.y, tm.t1.z, tm.t1.w, tm.m.y);
    s += cell_loss(p2.z, p2.w, p3.x, p3.y, p3.z,
                   tm.t2.x, tm.t2.y, tm.t2.z, tm.t2.w, tm.m.z);
    s += cell_loss(p3.w, p4.x, p4.y, p4.z, p4.w,
                   tm.t3.x, tm.t3.y, tm.t3.z, tm.t3.w, tm.m.w);
    return s;
}

__global__ __launch_bounds__(256) void yolo_loss_kernel(
    const char* __restrict__ predB,
    const f4*  __restrict__ targ4,
    const i4*  __restrict__ mask4,
    float* __restrict__ out,
    int ntiles)
{
    __shared__ char smem[2 * PRED_TILE_B];   // 40 KB -> 4 blocks/CU

    const int t    = threadIdx.x;
    const int lane = t & 63;
    const int wave = t >> 6;
    const int stride = gridDim.x;
    float acc = 0.0f;

    int idx = blockIdx.x;                              // grid <= ntiles, so always >= 1 tile
    const int cnt = (ntiles - 1 - idx) / stride + 1;   // uniform within block

    TM A, B;
    stage_pred(predB, smem, idx, wave, lane);          // tile0 -> buf0
    load_tm(A, targ4, mask4, idx * TILE_GROUPS + t);

    int done = 0;
    while (done + 2 <= cnt - 1) {                      // two pipelined steps per pass
        int n1 = idx + stride, n2 = idx + 2 * stride;
        stage_pred(predB, smem + PRED_TILE_B, n1, wave, lane);
        load_tm(B, targ4, mask4, n1 * TILE_GROUPS + t);
        PIPE_WAIT_BARRIER_10();
        acc += compute_tile(smem, A, t);
        PIPE_END_BARRIER();

        stage_pred(predB, smem, n2, wave, lane);
        load_tm(A, targ4, mask4, n2 * TILE_GROUPS + t);
        PIPE_WAIT_BARRIER_10();
        acc += compute_tile(smem + PRED_TILE_B, B, t);
        PIPE_END_BARRIER();

        idx = n2;
        done += 2;
    }
    if (done < cnt - 1) {                              // one more pipelined step; tail in buf1
        int n1 = idx + stride;
        stage_pred(predB, smem + PRED_TILE_B, n1, wave, lane);
        load_tm(B, targ4, mask4, n1 * TILE_GROUPS + t);
        PIPE_WAIT_BARRIER_10();
        acc += compute_tile(smem, A, t);
        PIPE_END_BARRIER();

        PIPE_WAIT_BARRIER_0();
        acc += compute_tile(smem + PRED_TILE_B, B, t);
    } else {                                           // tail in buf0
        PIPE_WAIT_BARRIER_0();
        acc += compute_tile(smem, A, t);
    }

    // wave (64-lane) shuffle reduction, then one atomic per wave (no LDS needed)
    #pragma unroll
    for (int off = 32; off > 0; off >>= 1)
        acc += __shfl_down(acc, off, 64);
    if (lane == 0)
        atomicAdd(out, acc * (1.0f / 1024.0f));
}

extern "C" void kernel_launch(void* const* d_in, const int* in_sizes, int n_in,
                              void* d_out, int out_size, void* d_ws, size_t ws_size,
                              hipStream_t stream) {
    const char* predB = (const char*)d_in[0];   // [1024,80,80,5] f32
    const f4*   targ4 = (const f4*)d_in[1];     // [1024,80,80,4] f32
    const i4*   mask4 = (const i4*)d_in[2];     // [1024,80,80]   i32
    float* out = (float*)d_out;

    int ncells = in_sizes[2];                   // 6,553,600
    int ntiles = ncells / (4 * TILE_GROUPS);    // 6400 tiles of 1024 cells

    zero_out_kernel<<<1, 1, 0, stream>>>(out);

    const int block = 256;
    const int grid = 2048;                      // cnt = 3 or 4 tiles per block
    yolo_loss_kernel<<<grid, block, 0, stream>>>(predB, targ4, mask4, out, ntiles);
}